// Round 7
// baseline (322.879 us; speedup 1.0000x reference)
//
#include <hip/hip_runtime.h>
#include <hip/hip_bf16.h>
#include <hip/hip_cooperative_groups.h>

namespace cg = cooperative_groups;

// SAGEConv mean-aggr: out_i = mean_{j->i} x_j @ W_l^T + b_l + x_i @ W_r^T
//
// R1: global fp32 atomics write through L2 -> 300 MB, 481 us. Dead end.
// R2: 49x redundant dst-scan, latency-bound -> 365 us.
// R3: counting-sort by dst-bucket + LDS fp-atomic agg -> 200 us.
// R4: fp32 LDS atomicAdd is a CAS loop (flavor/occupancy made no difference).
// R5: fixed-point u64 LDS atomics (native ds_add_u64) -> 141.7 us.
// R6: LDS weight staging REGRESSED (8.2M bank conflicts: lane k reads
//     stride-8-floats -> 4-way conflict, unpaddable). Reverted.
// R7: single persistent COOPERATIVE kernel, 256 blocks x 1024 thr (1/CU,
//     16 waves/CU): [proj || scatter] -> threadfence+grid.sync -> agg.
//     Eliminates dispatch gaps + ramp/tail of 7032 heterogeneous blocks;
//     weights via L1 (R5-style); agg LDS aliased over scatter histogram.

#define N_NODES 100000
#define N_EDGES 1600000
#define D_IN 128

#define HL_STRIDE 8

#define B_NODES 391                    // nodes per bucket
#define N_BUCKETS 256                  // 256*391 = 100096 >= N_NODES
#define CAP 7168                       // mean 6256, sigma ~79 -> +11.5 sigma

#define NBLK 256
#define NTHR 1024
#define NGROUPS (NBLK * (NTHR / 16))   // 16384 16-lane groups
#define EPB 6400                       // edges per scatter block; 250 blocks active

// fixed-point params for integer LDS accumulation
#define FXS 262144.0f                  // 2^18 scale
#define FXB 16777216u                  // 2^24 bias per addend
#define FXBF 16777216.0f
#define INV_FXS (1.0f / 262144.0f)

typedef unsigned long long u64;
typedef unsigned int u32;

__global__ __launch_bounds__(NTHR, 4) void mega_kernel(
    const float* __restrict__ x,
    const float* __restrict__ Wl,
    const float* __restrict__ Wr,
    float* __restrict__ hl,             // [N_NODES][8], first 5 valid
    float* __restrict__ hr,             // [N_NODES][8], first 5 valid
    const int* __restrict__ ei,         // [2][N_EDGES]: row0 src, row1 dst
    u32* __restrict__ sorted,           // [N_BUCKETS][CAP]
    int* __restrict__ cursor,           // [N_BUCKETS], zeroed by memset
    const float* __restrict__ bias,
    float* __restrict__ out)
{
    __shared__ u64 acc[B_NODES * 3];    // 9384 B; phase A aliases hist/basepos
    int* hist    = (int*)acc;           // [256]
    int* basepos = hist + N_BUCKETS;    // [256]

    const int tid = threadIdx.x;
    const int b   = blockIdx.x;

    // ================= phase A1: projection (grid-stride groups) ===========
    {
        const int k  = tid & 15;
        for (int node = b * (NTHR / 16) + (tid >> 4); node < N_NODES;
             node += NGROUPS) {
            const float4* xr = (const float4*)(x + (size_t)node * D_IN + k * 8);
            float4 x0 = xr[0];
            float4 x1 = xr[1];

            float s[10];
#pragma unroll
            for (int o = 0; o < 10; ++o) {
                const float* w = (o < 5 ? Wl + o * D_IN : Wr + (o - 5) * D_IN) + k * 8;
                float4 w0 = ((const float4*)w)[0];
                float4 w1 = ((const float4*)w)[1];
                s[o] = x0.x * w0.x + x0.y * w0.y + x0.z * w0.z + x0.w * w0.w
                     + x1.x * w1.x + x1.y * w1.y + x1.z * w1.z + x1.w * w1.w;
            }

#pragma unroll
            for (int o = 0; o < 10; ++o) {
                s[o] += __shfl_xor(s[o], 8, 64);
                s[o] += __shfl_xor(s[o], 4, 64);
                s[o] += __shfl_xor(s[o], 2, 64);
                s[o] += __shfl_xor(s[o], 1, 64);
            }

            if (k == 0) {
                float* pl = hl + (size_t)node * HL_STRIDE;
                *(float4*)pl = make_float4(s[0], s[1], s[2], s[3]);
                pl[4] = s[4];
                float* pr = hr + (size_t)node * HL_STRIDE;
                *(float4*)pr = make_float4(s[5], s[6], s[7], s[8]);
                pr[4] = s[9];
            }
        }
    }

    // ================= phase A2: counting-sort scatter ======================
    {
        if (tid < N_BUCKETS) hist[tid] = 0;
        __syncthreads();

        const bool active = (b < N_EDGES / EPB);   // blocks 0..249
        int sa[8], da[8], slot[8];
        bool hasB = false;

        if (active) {
            const int e0 = b * EPB;
            const int eA = e0 + tid * 4;           // tid*4 < 4096 < EPB always
            int4 s4 = *(const int4*)(ei + eA);
            int4 d4 = *(const int4*)(ei + N_EDGES + eA);
            sa[0]=s4.x; sa[1]=s4.y; sa[2]=s4.z; sa[3]=s4.w;
            da[0]=d4.x; da[1]=d4.y; da[2]=d4.z; da[3]=d4.w;
            hasB = (4096 + tid * 4) < EPB;         // tid < 576
            if (hasB) {
                const int eB = e0 + 4096 + tid * 4;
                int4 s5 = *(const int4*)(ei + eB);
                int4 d5 = *(const int4*)(ei + N_EDGES + eB);
                sa[4]=s5.x; sa[5]=s5.y; sa[6]=s5.z; sa[7]=s5.w;
                da[4]=d5.x; da[5]=d5.y; da[6]=d5.z; da[7]=d5.w;
            }

#pragma unroll
            for (int q = 0; q < 4; ++q) {
                unsigned bk = (unsigned)da[q] / 391u;
                slot[q] = atomicAdd(&hist[bk], 1);
            }
            if (hasB) {
#pragma unroll
                for (int q = 4; q < 8; ++q) {
                    unsigned bk = (unsigned)da[q] / 391u;
                    slot[q] = atomicAdd(&hist[bk], 1);
                }
            }
        }
        __syncthreads();

        if (tid < N_BUCKETS) {
            int c = hist[tid];
            basepos[tid] = (c > 0) ? atomicAdd(&cursor[tid], c) : 0;
        }
        __syncthreads();

        if (active) {
#pragma unroll
            for (int q = 0; q < 4; ++q) {
                unsigned bk = (unsigned)da[q] / 391u;
                unsigned r  = (unsigned)da[q] - bk * 391u;
                sorted[(size_t)bk * CAP + basepos[bk] + slot[q]] =
                    (r << 17) | (unsigned)sa[q];
            }
            if (hasB) {
#pragma unroll
                for (int q = 4; q < 8; ++q) {
                    unsigned bk = (unsigned)da[q] / 391u;
                    unsigned r  = (unsigned)da[q] - bk * 391u;
                    sorted[(size_t)bk * CAP + basepos[bk] + slot[q]] =
                        (r << 17) | (unsigned)sa[q];
                }
            }
        }
    }

    // ================= grid-wide barrier ====================================
    __threadfence();
    cg::this_grid().sync();

    // ================= phase C: per-bucket aggregation + finalize ===========
    {
        for (int i = tid; i < B_NODES * 3; i += NTHR) acc[i] = 0ull;
        __syncthreads();

        const int cnt = cursor[b];
        const u32* sp = sorted + (size_t)b * CAP;
        const int nvec = cnt >> 2;

#define EMIT(hh, ee, rr)                                                     \
        {                                                                    \
            u32 f0 = __float2uint_rn(fmaf((hh).x, FXS, FXBF));               \
            u32 f1 = __float2uint_rn(fmaf((hh).y, FXS, FXBF));               \
            u32 f2 = __float2uint_rn(fmaf((hh).z, FXS, FXBF));               \
            u32 f3 = __float2uint_rn(fmaf((hh).w, FXS, FXBF));               \
            u32 f4 = __float2uint_rn(fmaf((ee),   FXS, FXBF));               \
            u64* a = acc + (rr) * 3;                                         \
            atomicAdd(&a[0], ((u64)f1 << 32) | f0);                          \
            atomicAdd(&a[1], ((u64)f3 << 32) | f2);                          \
            atomicAdd(&a[2], ((u64)f4 << 32) | 1u);                          \
        }

        for (int it = tid; it < nvec; it += NTHR) {
            uint4 v = ((const uint4*)sp)[it];
            int s0 = (int)(v.x & 0x1FFFFu), r0 = (int)(v.x >> 17);
            int s1 = (int)(v.y & 0x1FFFFu), r1 = (int)(v.y >> 17);
            int s2 = (int)(v.z & 0x1FFFFu), r2 = (int)(v.z >> 17);
            int s3 = (int)(v.w & 0x1FFFFu), r3 = (int)(v.w >> 17);

            const float* p0 = hl + (size_t)s0 * HL_STRIDE;
            const float* p1 = hl + (size_t)s1 * HL_STRIDE;
            const float* p2 = hl + (size_t)s2 * HL_STRIDE;
            const float* p3 = hl + (size_t)s3 * HL_STRIDE;
            float4 h0 = *(const float4*)p0; float e0 = p0[4];
            float4 h1 = *(const float4*)p1; float e1 = p1[4];
            float4 h2 = *(const float4*)p2; float e2 = p2[4];
            float4 h3 = *(const float4*)p3; float e3 = p3[4];

            EMIT(h0, e0, r0) EMIT(h1, e1, r1) EMIT(h2, e2, r2) EMIT(h3, e3, r3)
        }
        for (int i = (nvec << 2) + tid; i < cnt; i += NTHR) {
            u32 v = sp[i];
            int src = (int)(v & 0x1FFFFu);
            int r   = (int)(v >> 17);
            const float* p = hl + (size_t)src * HL_STRIDE;
            float4 h = *(const float4*)p;
            float  e = p[4];
            EMIT(h, e, r)
        }
#undef EMIT
        __syncthreads();

        const int nodebase = b * B_NODES;
        for (int n = tid; n < B_NODES; n += NTHR) {
            int node = nodebase + n;
            if (node >= N_NODES) continue;
            u64 w0 = acc[n * 3 + 0];
            u64 w1 = acc[n * 3 + 1];
            u64 w2 = acc[n * 3 + 2];
            u32 deg = (u32)(w2 & 0xFFFFFFFFu);
            u32 db  = deg * FXB;        // wraparound-safe: true values fit i32
            int i0 = (int)((u32)(w0 & 0xFFFFFFFFu) - db);
            int i1 = (int)((u32)(w0 >> 32)         - db);
            int i2 = (int)((u32)(w1 & 0xFFFFFFFFu) - db);
            int i3 = (int)((u32)(w1 >> 32)         - db);
            int i4 = (int)((u32)(w2 >> 32)         - db);

            float rec = INV_FXS / fmaxf((float)deg, 1.0f);
            const float* h = hr + (size_t)node * HL_STRIDE;
            float* o = out + (size_t)node * 5;
            o[0] = (float)i0 * rec + bias[0] + h[0];
            o[1] = (float)i1 * rec + bias[1] + h[1];
            o[2] = (float)i2 * rec + bias[2] + h[2];
            o[3] = (float)i3 * rec + bias[3] + h[3];
            o[4] = (float)i4 * rec + bias[4] + h[4];
        }
    }
}

extern "C" void kernel_launch(void* const* d_in, const int* in_sizes, int n_in,
                              void* d_out, int out_size, void* d_ws, size_t ws_size,
                              hipStream_t stream) {
    const float* x    = (const float*)d_in[0];
    const int*   ei   = (const int*)d_in[1];
    const float* Wl   = (const float*)d_in[2];
    const float* bl   = (const float*)d_in[3];
    const float* Wr   = (const float*)d_in[4];
    float*       out  = (float*)d_out;

    // workspace layout (16B-aligned): ~13.8 MB total
    float* hl   = (float*)d_ws;                                   // 800000 f
    float* hr   = hl + (size_t)N_NODES * HL_STRIDE;               // 800000 f
    u32*   sorted = (u32*)(hr + (size_t)N_NODES * HL_STRIDE);     // 256*7168 u32
    int*   cursor = (int*)(sorted + (size_t)N_BUCKETS * CAP);     // 256 i32

    hipMemsetAsync(cursor, 0, N_BUCKETS * sizeof(int), stream);

    void* args[] = {
        (void*)&x, (void*)&Wl, (void*)&Wr, (void*)&hl, (void*)&hr,
        (void*)&ei, (void*)&sorted, (void*)&cursor, (void*)&bl, (void*)&out
    };
    hipLaunchCooperativeKernel((void*)mega_kernel, dim3(NBLK), dim3(NTHR),
                               args, 0, stream);
}

// Round 8
// 135.253 us; speedup vs baseline: 2.3872x; 2.3872x over previous
//
#include <hip/hip_runtime.h>
#include <hip/hip_bf16.h>

// SAGEConv mean-aggr: out_i = mean_{j->i} x_j @ W_l^T + b_l + x_i @ W_r^T
//
// R1: global fp32 atomics write through L2 -> 300 MB, 481 us. Dead end.
// R2: 49x redundant dst-scan, latency-bound -> 365 us.
// R3: counting-sort by dst-bucket + LDS fp-atomic agg -> 200 us.
// R4: fp32 LDS atomicAdd is a CAS loop (flavor/occupancy made no difference).
// R5: fixed-point u64 LDS atomics (native ds_add_u64) -> 141.7 us. BEST.
// R6: LDS weight staging regressed (8.2M bank conflicts, 4-way, unpaddable).
// R7: persistent cooperative kernel regressed hard (322 us): grid.sync cost +
//     phase serialization + loss of inter-block overlap. Reverted.
// R8: R5 structure verbatim, ONE change: proj hoists the wave-uniform weights
//     into 80 VGPRs once per thread, then does 4 consecutive nodes per
//     16-lane group -> weight VMEM per node 20 -> 5, no LDS conflicts.
//     VGPR ~115, __launch_bounds__(256,4) keeps 4 waves/EU.

#define N_NODES 100000
#define N_EDGES 1600000
#define D_IN 128
#define D_OUT 5

#define HL_STRIDE 8

#define BSHIFT 8
#define B_NODES 256                    // nodes per bucket = 1<<BSHIFT
#define N_BUCKETS 392                  // ceil(100000/256)
#define CAP 5120                       // mean 4082, sigma ~64 -> +16 sigma

#define SC_EPT 8                       // edges per scatter thread
#define SC_EPB (256 * SC_EPT)          // 2048 edges per scatter block
#define SC_GRID ((N_EDGES + SC_EPB - 1) / SC_EPB)   // 782

#define PROJ_NPB 64                    // nodes per proj block (16 groups x 4)
#define PROJ_BLOCKS ((N_NODES + PROJ_NPB - 1) / PROJ_NPB)   // 1563
#define FUSED_GRID (PROJ_BLOCKS + SC_GRID)                  // 2345

// fixed-point params for integer LDS accumulation
#define FXS 262144.0f                  // 2^18 scale
#define FXB 16777216u                  // 2^24 bias per addend
#define FXBF 16777216.0f
#define INV_FXS (1.0f / 262144.0f)

typedef unsigned long long u64;
typedef unsigned int u32;

// ---------------------------------------------------------------------------
// Fused kernel A: blocks [0, PROJ_BLOCKS) projection; rest counting-sort
// scatter (R5 form).
// ---------------------------------------------------------------------------
__global__ __launch_bounds__(256, 4) void proj_scatter_kernel(
    const float* __restrict__ x,
    const float* __restrict__ Wl,
    const float* __restrict__ Wr,
    float* __restrict__ hl,             // [N_NODES][8], first 5 valid
    float* __restrict__ hr,             // [N_NODES][8], first 5 valid
    const int* __restrict__ ei,         // [2][N_EDGES]: row0 src, row1 dst
    unsigned int* __restrict__ sorted,  // [N_BUCKETS][CAP]
    int* __restrict__ cursor)           // [N_BUCKETS], zero-initialized
{
    const int tid = threadIdx.x;

    if (blockIdx.x < PROJ_BLOCKS) {
        // ---------------- projection ----------------
        const int g = tid >> 4;          // group 0..15
        const int k = tid & 15;          // lane within group, dims [8k,8k+8)

        // hoist weights into registers: 10 rows x 8 floats = 80 VGPRs
        float4 wv[10][2];
#pragma unroll
        for (int o = 0; o < 10; ++o) {
            const float* w = (o < 5 ? Wl + o * D_IN : Wr + (o - 5) * D_IN) + k * 8;
            wv[o][0] = ((const float4*)w)[0];
            wv[o][1] = ((const float4*)w)[1];
        }

        const int node0 = blockIdx.x * PROJ_NPB + g * 4;

#pragma unroll
        for (int it = 0; it < 4; ++it) {
            const int node = node0 + it;
            if (node < N_NODES) {
                const float4* xr = (const float4*)(x + (size_t)node * D_IN + k * 8);
                float4 x0 = xr[0];
                float4 x1 = xr[1];

                float s[10];
#pragma unroll
                for (int o = 0; o < 10; ++o) {
                    s[o] = x0.x * wv[o][0].x + x0.y * wv[o][0].y
                         + x0.z * wv[o][0].z + x0.w * wv[o][0].w
                         + x1.x * wv[o][1].x + x1.y * wv[o][1].y
                         + x1.z * wv[o][1].z + x1.w * wv[o][1].w;
                }

#pragma unroll
                for (int o = 0; o < 10; ++o) {
                    s[o] += __shfl_xor(s[o], 8, 64);
                    s[o] += __shfl_xor(s[o], 4, 64);
                    s[o] += __shfl_xor(s[o], 2, 64);
                    s[o] += __shfl_xor(s[o], 1, 64);
                }

                if (k == 0) {
                    float* pl = hl + (size_t)node * HL_STRIDE;
                    *(float4*)pl = make_float4(s[0], s[1], s[2], s[3]);
                    pl[4] = s[4];
                    float* pr = hr + (size_t)node * HL_STRIDE;
                    *(float4*)pr = make_float4(s[5], s[6], s[7], s[8]);
                    pr[4] = s[9];
                }
            }
        }
    } else {
        // ---------------- counting-sort scatter (R5 verbatim) ----------------
        __shared__ int hist[N_BUCKETS];
        __shared__ int basepos[N_BUCKETS];

        for (int i = tid; i < N_BUCKETS; i += 256) hist[i] = 0;
        __syncthreads();

        const int blk = blockIdx.x - PROJ_BLOCKS;
        const int e0  = blk * SC_EPB + tid * SC_EPT;

        int srcv[SC_EPT], dstv[SC_EPT], slot[SC_EPT];
        bool valid[SC_EPT];

        if (e0 + SC_EPT <= N_EDGES) {
            const int4* s4 = (const int4*)(ei + e0);
            const int4* d4 = (const int4*)(ei + N_EDGES + e0);
            int4 sa = s4[0], sb = s4[1], da = d4[0], db = d4[1];
            srcv[0]=sa.x; srcv[1]=sa.y; srcv[2]=sa.z; srcv[3]=sa.w;
            srcv[4]=sb.x; srcv[5]=sb.y; srcv[6]=sb.z; srcv[7]=sb.w;
            dstv[0]=da.x; dstv[1]=da.y; dstv[2]=da.z; dstv[3]=da.w;
            dstv[4]=db.x; dstv[5]=db.y; dstv[6]=db.z; dstv[7]=db.w;
#pragma unroll
            for (int q = 0; q < SC_EPT; ++q) valid[q] = true;
        } else {
#pragma unroll
            for (int q = 0; q < SC_EPT; ++q) {
                int e = e0 + q;
                valid[q] = (e < N_EDGES);
                srcv[q] = valid[q] ? ei[e] : 0;
                dstv[q] = valid[q] ? ei[N_EDGES + e] : 0;
            }
        }

#pragma unroll
        for (int q = 0; q < SC_EPT; ++q) {
            if (valid[q]) {
                int b = dstv[q] >> BSHIFT;
                slot[q] = atomicAdd(&hist[b], 1);
            }
        }
        __syncthreads();

        for (int b = tid; b < N_BUCKETS; b += 256) {
            int c = hist[b];
            if (c > 0) basepos[b] = atomicAdd(&cursor[b], c);
        }
        __syncthreads();

#pragma unroll
        for (int q = 0; q < SC_EPT; ++q) {
            if (valid[q]) {
                int b = dstv[q] >> BSHIFT;
                int r = dstv[q] & (B_NODES - 1);
                unsigned int rec = ((unsigned int)r << 17) | (unsigned int)srcv[q];
                sorted[(size_t)b * CAP + basepos[b] + slot[q]] = rec;
            }
        }
    }
}

// ---------------------------------------------------------------------------
// Kernel B: per-bucket aggregation via native u64 LDS atomics (R5 verbatim,
// fixed-point biased fields: f*2^18 + 2^24/addend; deg<=~64 -> sums < 2^31).
// ---------------------------------------------------------------------------
__global__ __launch_bounds__(1024) void agg_kernel(
    const unsigned int* __restrict__ sorted,
    const int* __restrict__ cursor,
    const float* __restrict__ hl,
    const float* __restrict__ hr,
    const float* __restrict__ bias,
    float* __restrict__ out)
{
    __shared__ u64 acc[B_NODES * 3];   // 6 KB

    const int b   = blockIdx.x;
    const int tid = threadIdx.x;

    for (int i = tid; i < B_NODES * 3; i += 1024) acc[i] = 0ull;
    __syncthreads();

    const int cnt = cursor[b];
    const unsigned int* sp = sorted + (size_t)b * CAP;
    const int nvec = cnt >> 2;

#define EMIT(hh, ee, rr)                                                     \
    {                                                                        \
        u32 f0 = __float2uint_rn(fmaf((hh).x, FXS, FXBF));                   \
        u32 f1 = __float2uint_rn(fmaf((hh).y, FXS, FXBF));                   \
        u32 f2 = __float2uint_rn(fmaf((hh).z, FXS, FXBF));                   \
        u32 f3 = __float2uint_rn(fmaf((hh).w, FXS, FXBF));                   \
        u32 f4 = __float2uint_rn(fmaf((ee),   FXS, FXBF));                   \
        u64* a = acc + (rr) * 3;                                             \
        atomicAdd(&a[0], ((u64)f1 << 32) | f0);                              \
        atomicAdd(&a[1], ((u64)f3 << 32) | f2);                              \
        atomicAdd(&a[2], ((u64)f4 << 32) | 1u);                              \
    }

    for (int it = tid; it < nvec; it += 1024) {
        uint4 v = ((const uint4*)sp)[it];
        int s0 = (int)(v.x & 0x1FFFFu), r0 = (int)(v.x >> 17);
        int s1 = (int)(v.y & 0x1FFFFu), r1 = (int)(v.y >> 17);
        int s2 = (int)(v.z & 0x1FFFFu), r2 = (int)(v.z >> 17);
        int s3 = (int)(v.w & 0x1FFFFu), r3 = (int)(v.w >> 17);

        const float* p0 = hl + (size_t)s0 * HL_STRIDE;
        const float* p1 = hl + (size_t)s1 * HL_STRIDE;
        const float* p2 = hl + (size_t)s2 * HL_STRIDE;
        const float* p3 = hl + (size_t)s3 * HL_STRIDE;
        float4 h0 = *(const float4*)p0; float e0 = p0[4];
        float4 h1 = *(const float4*)p1; float e1 = p1[4];
        float4 h2 = *(const float4*)p2; float e2 = p2[4];
        float4 h3 = *(const float4*)p3; float e3 = p3[4];

        EMIT(h0, e0, r0) EMIT(h1, e1, r1) EMIT(h2, e2, r2) EMIT(h3, e3, r3)
    }
    for (int i = (nvec << 2) + tid; i < cnt; i += 1024) {
        unsigned int v = sp[i];
        int src = (int)(v & 0x1FFFFu);
        int r   = (int)(v >> 17);
        const float* p = hl + (size_t)src * HL_STRIDE;
        float4 h = *(const float4*)p;
        float  e = p[4];
        EMIT(h, e, r)
    }
#undef EMIT
    __syncthreads();

    const int nodebase = b << BSHIFT;
    for (int n = tid; n < B_NODES; n += 1024) {
        int node = nodebase + n;
        if (node >= N_NODES) continue;
        u64 w0 = acc[n * 3 + 0];
        u64 w1 = acc[n * 3 + 1];
        u64 w2 = acc[n * 3 + 2];
        u32 deg = (u32)(w2 & 0xFFFFFFFFu);
        u32 db  = deg * FXB;            // wraparound-safe: true values fit i32
        int i0 = (int)((u32)(w0 & 0xFFFFFFFFu) - db);
        int i1 = (int)((u32)(w0 >> 32)         - db);
        int i2 = (int)((u32)(w1 & 0xFFFFFFFFu) - db);
        int i3 = (int)((u32)(w1 >> 32)         - db);
        int i4 = (int)((u32)(w2 >> 32)         - db);

        float rec = INV_FXS / fmaxf((float)deg, 1.0f);
        const float* h = hr + (size_t)node * HL_STRIDE;
        float* o = out + (size_t)node * 5;
        o[0] = (float)i0 * rec + bias[0] + h[0];
        o[1] = (float)i1 * rec + bias[1] + h[1];
        o[2] = (float)i2 * rec + bias[2] + h[2];
        o[3] = (float)i3 * rec + bias[3] + h[3];
        o[4] = (float)i4 * rec + bias[4] + h[4];
    }
}

extern "C" void kernel_launch(void* const* d_in, const int* in_sizes, int n_in,
                              void* d_out, int out_size, void* d_ws, size_t ws_size,
                              hipStream_t stream) {
    const float* x    = (const float*)d_in[0];
    const int*   ei   = (const int*)d_in[1];
    const float* Wl   = (const float*)d_in[2];
    const float* bl   = (const float*)d_in[3];
    const float* Wr   = (const float*)d_in[4];
    float*       out  = (float*)d_out;

    // workspace layout (16B-aligned): ~14.4 MB total
    float*        hl     = (float*)d_ws;                              // 800000 f
    float*        hr     = hl + (size_t)N_NODES * HL_STRIDE;          // 800000 f
    unsigned int* sorted = (unsigned int*)(hr + (size_t)N_NODES * HL_STRIDE); // 392*5120 u32
    int*          cursor = (int*)(sorted + (size_t)N_BUCKETS * CAP);  // 392 i32

    hipMemsetAsync(cursor, 0, N_BUCKETS * sizeof(int), stream);

    proj_scatter_kernel<<<FUSED_GRID, 256, 0, stream>>>(
        x, Wl, Wr, hl, hr, ei, sorted, cursor);

    agg_kernel<<<N_BUCKETS, 1024, 0, stream>>>(sorted, cursor, hl, hr, bl, out);
}

// Round 9
// 130.875 us; speedup vs baseline: 2.4671x; 1.0335x over previous
//
#include <hip/hip_runtime.h>
#include <hip/hip_bf16.h>

// SAGEConv mean-aggr: out_i = mean_{j->i} x_j @ W_l^T + b_l + x_i @ W_r^T
//
// R1: global fp32 atomics write through L2 -> 300 MB, 481 us. Dead end.
// R2: 49x redundant dst-scan, latency-bound -> 365 us.
// R3: counting-sort by dst-bucket + LDS fp-atomic agg -> 200 us.
// R4: fp32 LDS atomicAdd is a CAS loop on gfx950 - never use it.
// R5: fixed-point u64 LDS atomics (native ds_add_u64) -> 141.7 us.
// R6: LDS weight staging regressed (8.2M 4-way bank conflicts, unpaddable).
// R7: persistent cooperative kernel regressed hard (322 us). Reverted.
// R8: weights hoisted to VGPRs (80/thread), 4 nodes/group -> 135.3 us. BEST.
//     Top-5 now dominated by the harness's 256MB d_ws poison fill (41 us)
//     -> both kernels < 41 us; ~55 us/iter is harness-fixed.
// R9: (a) proj: 8 nodes/group + branch-free clamp (idempotent dup of last
//         row) -> VMEM insts/node 1.75 -> 1.1, deeper load pipelining;
//     (b) agg: 512 buckets x 196 nodes, 512 thr -> exactly 2 blocks/CU,
//         no makespan tail (392x1024 wasted ~30% on 2-vs-1 block CUs).

#define N_NODES 100000
#define N_EDGES 1600000
#define D_IN 128

#define HL_STRIDE 8
#define N_PAD 100352                   // padded node count for clamp-free writes

#define B_NODES 196                    // nodes per bucket
#define N_BUCKETS 512                  // 512*196 = 100352 >= N_NODES
#define CAP 3840                       // mean 3125, sigma ~56 -> +12.8 sigma

#define SC_EPT 8
#define SC_EPB (256 * SC_EPT)          // 2048 edges per scatter block
#define SC_GRID ((N_EDGES + SC_EPB - 1) / SC_EPB)   // 782

#define NPG 8                          // nodes per 16-lane group
#define PROJ_NPB (16 * NPG)            // 128 nodes per proj block
#define PROJ_BLOCKS ((N_NODES + PROJ_NPB - 1) / PROJ_NPB)   // 782
#define FUSED_GRID (PROJ_BLOCKS + SC_GRID)                  // 1564

// fixed-point params for integer LDS accumulation
// per-addend field: f*2^18 + 2^24; deg<=116 keeps field sums < 2^31
#define FXS 262144.0f                  // 2^18 scale
#define FXB 16777216u                  // 2^24 bias per addend
#define FXBF 16777216.0f
#define INV_FXS (1.0f / 262144.0f)

typedef unsigned long long u64;
typedef unsigned int u32;

// ---------------------------------------------------------------------------
// Fused kernel A: blocks [0, PROJ_BLOCKS) projection; rest counting-sort
// scatter.
// ---------------------------------------------------------------------------
__global__ __launch_bounds__(256, 4) void proj_scatter_kernel(
    const float* __restrict__ x,
    const float* __restrict__ Wl,
    const float* __restrict__ Wr,
    float* __restrict__ hl,             // [N_PAD][8], first 5 valid
    float* __restrict__ hr,             // [N_PAD][8], first 5 valid
    const int* __restrict__ ei,         // [2][N_EDGES]: row0 src, row1 dst
    u32* __restrict__ sorted,           // [N_BUCKETS][CAP]
    int* __restrict__ cursor)           // [N_BUCKETS], zero-initialized
{
    const int tid = threadIdx.x;

    if (blockIdx.x < PROJ_BLOCKS) {
        // ---------------- projection ----------------
        const int g = tid >> 4;          // group 0..15
        const int k = tid & 15;          // lane within group, dims [8k,8k+8)

        // hoist weights into registers: 10 rows x 8 floats = 80 VGPRs
        float4 wv[10][2];
#pragma unroll
        for (int o = 0; o < 10; ++o) {
            const float* w = (o < 5 ? Wl + o * D_IN : Wr + (o - 5) * D_IN) + k * 8;
            wv[o][0] = ((const float4*)w)[0];
            wv[o][1] = ((const float4*)w)[1];
        }

        const int node0 = blockIdx.x * PROJ_NPB + g * NPG;

#pragma unroll
        for (int it = 0; it < NPG; ++it) {
            // branch-free clamp: nodes >= N_NODES recompute row N_NODES-1 and
            // overwrite it with identical values (idempotent, no divergence)
            const int node = min(node0 + it, N_NODES - 1);

            const float4* xr = (const float4*)(x + (size_t)node * D_IN + k * 8);
            float4 x0 = xr[0];
            float4 x1 = xr[1];

            float s[10];
#pragma unroll
            for (int o = 0; o < 10; ++o) {
                s[o] = x0.x * wv[o][0].x + x0.y * wv[o][0].y
                     + x0.z * wv[o][0].z + x0.w * wv[o][0].w
                     + x1.x * wv[o][1].x + x1.y * wv[o][1].y
                     + x1.z * wv[o][1].z + x1.w * wv[o][1].w;
            }

#pragma unroll
            for (int o = 0; o < 10; ++o) {
                s[o] += __shfl_xor(s[o], 8, 64);
                s[o] += __shfl_xor(s[o], 4, 64);
                s[o] += __shfl_xor(s[o], 2, 64);
                s[o] += __shfl_xor(s[o], 1, 64);
            }

            if (k == 0) {
                float* pl = hl + (size_t)node * HL_STRIDE;
                *(float4*)pl = make_float4(s[0], s[1], s[2], s[3]);
                pl[4] = s[4];
                float* pr = hr + (size_t)node * HL_STRIDE;
                *(float4*)pr = make_float4(s[5], s[6], s[7], s[8]);
                pr[4] = s[9];
            }
        }
    } else {
        // ---------------- counting-sort scatter ----------------
        __shared__ int hist[N_BUCKETS];
        __shared__ int basepos[N_BUCKETS];

        for (int i = tid; i < N_BUCKETS; i += 256) hist[i] = 0;
        __syncthreads();

        const int blk = blockIdx.x - PROJ_BLOCKS;
        const int e0  = blk * SC_EPB + tid * SC_EPT;

        int srcv[SC_EPT], dstv[SC_EPT], slot[SC_EPT];
        bool valid[SC_EPT];

        if (e0 + SC_EPT <= N_EDGES) {
            const int4* s4 = (const int4*)(ei + e0);
            const int4* d4 = (const int4*)(ei + N_EDGES + e0);
            int4 sa = s4[0], sb = s4[1], da = d4[0], db = d4[1];
            srcv[0]=sa.x; srcv[1]=sa.y; srcv[2]=sa.z; srcv[3]=sa.w;
            srcv[4]=sb.x; srcv[5]=sb.y; srcv[6]=sb.z; srcv[7]=sb.w;
            dstv[0]=da.x; dstv[1]=da.y; dstv[2]=da.z; dstv[3]=da.w;
            dstv[4]=db.x; dstv[5]=db.y; dstv[6]=db.z; dstv[7]=db.w;
#pragma unroll
            for (int q = 0; q < SC_EPT; ++q) valid[q] = true;
        } else {
#pragma unroll
            for (int q = 0; q < SC_EPT; ++q) {
                int e = e0 + q;
                valid[q] = (e < N_EDGES);
                srcv[q] = valid[q] ? ei[e] : 0;
                dstv[q] = valid[q] ? ei[N_EDGES + e] : 0;
            }
        }

#pragma unroll
        for (int q = 0; q < SC_EPT; ++q) {
            if (valid[q]) {
                unsigned b = (unsigned)dstv[q] / 196u;   // magic-mul div
                slot[q] = atomicAdd(&hist[b], 1);
            }
        }
        __syncthreads();

        for (int b = tid; b < N_BUCKETS; b += 256) {
            int c = hist[b];
            if (c > 0) basepos[b] = atomicAdd(&cursor[b], c);
        }
        __syncthreads();

#pragma unroll
        for (int q = 0; q < SC_EPT; ++q) {
            if (valid[q]) {
                unsigned b = (unsigned)dstv[q] / 196u;
                unsigned r = (unsigned)dstv[q] - b * 196u;
                sorted[(size_t)b * CAP + basepos[b] + slot[q]] =
                    (r << 17) | (unsigned)srcv[q];
            }
        }
    }
}

// ---------------------------------------------------------------------------
// Kernel B: per-bucket aggregation via native u64 LDS atomics, fixed-point
// biased fields. 512 blocks x 512 threads = exactly 2 blocks/CU.
// ---------------------------------------------------------------------------
__global__ __launch_bounds__(512) void agg_kernel(
    const u32* __restrict__ sorted,
    const int* __restrict__ cursor,
    const float* __restrict__ hl,
    const float* __restrict__ hr,
    const float* __restrict__ bias,
    float* __restrict__ out)
{
    __shared__ u64 acc[B_NODES * 3];   // 4.7 KB

    const int b   = blockIdx.x;
    const int tid = threadIdx.x;

    for (int i = tid; i < B_NODES * 3; i += 512) acc[i] = 0ull;
    __syncthreads();

    const int cnt = cursor[b];
    const u32* sp = sorted + (size_t)b * CAP;
    const int nvec = cnt >> 2;

#define EMIT(hh, ee, rr)                                                     \
    {                                                                        \
        u32 f0 = __float2uint_rn(fmaf((hh).x, FXS, FXBF));                   \
        u32 f1 = __float2uint_rn(fmaf((hh).y, FXS, FXBF));                   \
        u32 f2 = __float2uint_rn(fmaf((hh).z, FXS, FXBF));                   \
        u32 f3 = __float2uint_rn(fmaf((hh).w, FXS, FXBF));                   \
        u32 f4 = __float2uint_rn(fmaf((ee),   FXS, FXBF));                   \
        u64* a = acc + (rr) * 3;                                             \
        atomicAdd(&a[0], ((u64)f1 << 32) | f0);                              \
        atomicAdd(&a[1], ((u64)f3 << 32) | f2);                              \
        atomicAdd(&a[2], ((u64)f4 << 32) | 1u);                              \
    }

    for (int it = tid; it < nvec; it += 512) {
        uint4 v = ((const uint4*)sp)[it];
        int s0 = (int)(v.x & 0x1FFFFu), r0 = (int)(v.x >> 17);
        int s1 = (int)(v.y & 0x1FFFFu), r1 = (int)(v.y >> 17);
        int s2 = (int)(v.z & 0x1FFFFu), r2 = (int)(v.z >> 17);
        int s3 = (int)(v.w & 0x1FFFFu), r3 = (int)(v.w >> 17);

        const float* p0 = hl + (size_t)s0 * HL_STRIDE;
        const float* p1 = hl + (size_t)s1 * HL_STRIDE;
        const float* p2 = hl + (size_t)s2 * HL_STRIDE;
        const float* p3 = hl + (size_t)s3 * HL_STRIDE;
        float4 h0 = *(const float4*)p0; float e0 = p0[4];
        float4 h1 = *(const float4*)p1; float e1 = p1[4];
        float4 h2 = *(const float4*)p2; float e2 = p2[4];
        float4 h3 = *(const float4*)p3; float e3 = p3[4];

        EMIT(h0, e0, r0) EMIT(h1, e1, r1) EMIT(h2, e2, r2) EMIT(h3, e3, r3)
    }
    for (int i = (nvec << 2) + tid; i < cnt; i += 512) {
        u32 v = sp[i];
        int src = (int)(v & 0x1FFFFu);
        int r   = (int)(v >> 17);
        const float* p = hl + (size_t)src * HL_STRIDE;
        float4 h = *(const float4*)p;
        float  e = p[4];
        EMIT(h, e, r)
    }
#undef EMIT
    __syncthreads();

    const int nodebase = b * B_NODES;
    for (int n = tid; n < B_NODES; n += 512) {
        int node = nodebase + n;
        if (node >= N_NODES) continue;
        u64 w0 = acc[n * 3 + 0];
        u64 w1 = acc[n * 3 + 1];
        u64 w2 = acc[n * 3 + 2];
        u32 deg = (u32)(w2 & 0xFFFFFFFFu);
        u32 db  = deg * FXB;            // wraparound-safe: true values fit i32
        int i0 = (int)((u32)(w0 & 0xFFFFFFFFu) - db);
        int i1 = (int)((u32)(w0 >> 32)         - db);
        int i2 = (int)((u32)(w1 & 0xFFFFFFFFu) - db);
        int i3 = (int)((u32)(w1 >> 32)         - db);
        int i4 = (int)((u32)(w2 >> 32)         - db);

        float rec = INV_FXS / fmaxf((float)deg, 1.0f);
        const float* h = hr + (size_t)node * HL_STRIDE;
        float* o = out + (size_t)node * 5;
        o[0] = (float)i0 * rec + bias[0] + h[0];
        o[1] = (float)i1 * rec + bias[1] + h[1];
        o[2] = (float)i2 * rec + bias[2] + h[2];
        o[3] = (float)i3 * rec + bias[3] + h[3];
        o[4] = (float)i4 * rec + bias[4] + h[4];
    }
}

extern "C" void kernel_launch(void* const* d_in, const int* in_sizes, int n_in,
                              void* d_out, int out_size, void* d_ws, size_t ws_size,
                              hipStream_t stream) {
    const float* x    = (const float*)d_in[0];
    const int*   ei   = (const int*)d_in[1];
    const float* Wl   = (const float*)d_in[2];
    const float* bl   = (const float*)d_in[3];
    const float* Wr   = (const float*)d_in[4];
    float*       out  = (float*)d_out;

    // workspace layout (16B-aligned): ~14.3 MB total
    float* hl     = (float*)d_ws;                                 // N_PAD*8 f
    float* hr     = hl + (size_t)N_PAD * HL_STRIDE;               // N_PAD*8 f
    u32*   sorted = (u32*)(hr + (size_t)N_PAD * HL_STRIDE);       // 512*3840 u32
    int*   cursor = (int*)(sorted + (size_t)N_BUCKETS * CAP);     // 512 i32

    hipMemsetAsync(cursor, 0, N_BUCKETS * sizeof(int), stream);

    proj_scatter_kernel<<<FUSED_GRID, 256, 0, stream>>>(
        x, Wl, Wr, hl, hr, ei, sorted, cursor);

    agg_kernel<<<N_BUCKETS, 512, 0, stream>>>(sorted, cursor, hl, hr, bl, out);
}